// Round 12
// baseline (296.263 us; speedup 1.0000x reference)
//
#include <hip/hip_runtime.h>
#include <hip/hip_bf16.h>
#include <math.h>

#define NN 100000
#define NE 1600000
#define INF_ 256
#define OF 64

#define NPB 128                      // nodes per bucket (bucket = src >> 7)
#define NB  782                      // ceil(NN/NPB)
#define CAPB 2560                    // fixed bucket capacity (mean 2048, +11 sigma)
#define ED (CAPB + 128)
#define GEMMB 782                    // ceil(NN/128) gemm blocks
#define P1B 512                      // part1 blocks
#define CH1 ((NE + P1B - 1) / P1B)   // 3125 edges/block
#define OVCAP 8192

constexpr float LRELU_ALPHA = 0.2f;

typedef __attribute__((ext_vector_type(8))) short short8;
typedef __attribute__((ext_vector_type(4))) float f32x4;

static __device__ __forceinline__ unsigned short f2bf(float f) {
    union { float f; unsigned int u; } v; v.f = f;
    unsigned int r = v.u + 0x7fff + ((v.u >> 16) & 1);   // RNE
    return (unsigned short)(r >> 16);
}
static __device__ __forceinline__ float bf2f(unsigned short b) {
    union { unsigned int u; float f; } v; v.u = ((unsigned int)b) << 16;
    return v.f;
}
static __device__ __forceinline__ unsigned int pkbf(float a, float b) {
    union { __hip_bfloat162 h; unsigned int u; } c;
    c.h = __float22bfloat162_rn(make_float2(a, b));
    return c.u;
}

union S8 { short8 s; unsigned int u[4]; };

// ---------------- wa1 = W @ a1, wa2 = W @ a2 ----------------
__global__ __launch_bounds__(256) void k_prep(const float* __restrict__ W,
                                              const float* __restrict__ a,
                                              float* __restrict__ wa) {
    int r = threadIdx.x;
    float t1 = 0.f, t2 = 0.f;
#pragma unroll 8
    for (int c = 0; c < OF; ++c) {
        float w = W[r * OF + c];
        t1 += w * a[c];
        t2 += w * a[OF + c];
    }
    wa[r] = t1;
    wa[256 + r] = t2;
}

// ======= gemm: 40960B LDS (4 blocks/CU), 2-stage pipelined x loads =======
__global__ __launch_bounds__(256, 4) void k_gemm(const float* __restrict__ x,
                                                 const float* __restrict__ W,
                                                 const float* __restrict__ wa,
                                                 unsigned short* __restrict__ h,
                                                 float* __restrict__ s1,
                                                 float* __restrict__ s2) {
    __shared__ short Wf[2560 * 8];     // [ks(8)][ct(5)][lane(64)][8 bf16] = 40960 B exactly
    int tid = threadIdx.x;
    for (int i = tid; i < 2560; i += 256) {
        int ks = i / 320;
        int rem = i - ks * 320;
        int ct = rem >> 6;
        int l  = rem & 63;
        int kb = ks * 32 + ((l >> 4) << 3);
        int c  = l & 15;
        S8 v;
        if (ct < 4) {
            int col = ct * 16 + c;
#pragma unroll
            for (int j = 0; j < 4; ++j)
                v.u[j] = pkbf(W[(size_t)(kb + 2 * j) * OF + col],
                              W[(size_t)(kb + 2 * j + 1) * OF + col]);
        } else if (c < 2) {
            const float* src = wa + c * 256;       // global, L2-hot (2 KB)
#pragma unroll
            for (int j = 0; j < 4; ++j)
                v.u[j] = pkbf(src[kb + 2 * j], src[kb + 2 * j + 1]);
        } else {
#pragma unroll
            for (int j = 0; j < 4; ++j) v.u[j] = 0u;
        }
        ((short8*)Wf)[i] = v.s;
    }
    __syncthreads();

    int wid = tid >> 6, lane = tid & 63;
    int rowbase = blockIdx.x * 128 + wid * 32;
    int r0 = rowbase + (lane & 15);
    int koff = (lane >> 4) << 3;
    bool ok0 = (r0 < NN), ok1 = (r0 + 16 < NN);
    const float* p0 = x + (size_t)r0 * INF_ + koff;
    const float* p1 = p0 + (size_t)16 * INF_;

    f32x4 acc[2][5];
#pragma unroll
    for (int rt = 0; rt < 2; ++rt)
#pragma unroll
        for (int ct = 0; ct < 5; ++ct) acc[rt][ct] = (f32x4){0.f, 0.f, 0.f, 0.f};

    // 2-stage software pipeline: issue ks+1 loads before ks MFMAs
    float4 ca0, cb0, ca1, cb1;        // current
    float4 na0, nb0, na1, nb1;        // next
    ca0 = ok0 ? *(const float4*)p0 : make_float4(0, 0, 0, 0);
    cb0 = ok0 ? *(const float4*)(p0 + 4) : make_float4(0, 0, 0, 0);
    ca1 = ok1 ? *(const float4*)p1 : make_float4(0, 0, 0, 0);
    cb1 = ok1 ? *(const float4*)(p1 + 4) : make_float4(0, 0, 0, 0);

#pragma unroll 1
    for (int ks = 0; ks < 8; ++ks) {
        if (ks < 7) {
            const float* q0 = p0 + (ks + 1) * 32;
            const float* q1 = p1 + (ks + 1) * 32;
            na0 = ok0 ? *(const float4*)q0 : make_float4(0, 0, 0, 0);
            nb0 = ok0 ? *(const float4*)(q0 + 4) : make_float4(0, 0, 0, 0);
            na1 = ok1 ? *(const float4*)q1 : make_float4(0, 0, 0, 0);
            nb1 = ok1 ? *(const float4*)(q1 + 4) : make_float4(0, 0, 0, 0);
        }
        S8 af[2];
        af[0].u[0] = pkbf(ca0.x, ca0.y); af[0].u[1] = pkbf(ca0.z, ca0.w);
        af[0].u[2] = pkbf(cb0.x, cb0.y); af[0].u[3] = pkbf(cb0.z, cb0.w);
        af[1].u[0] = pkbf(ca1.x, ca1.y); af[1].u[1] = pkbf(ca1.z, ca1.w);
        af[1].u[2] = pkbf(cb1.x, cb1.y); af[1].u[3] = pkbf(cb1.z, cb1.w);
#pragma unroll
        for (int rt = 0; rt < 2; ++rt)
#pragma unroll
            for (int ct = 0; ct < 5; ++ct)
                acc[rt][ct] = __builtin_amdgcn_mfma_f32_16x16x32_bf16(
                    af[rt].s, ((short8*)Wf)[(ks * 5 + ct) * 64 + lane], acc[rt][ct], 0, 0, 0);
        ca0 = na0; cb0 = nb0; ca1 = na1; cb1 = nb1;
    }

    int c = lane & 15, rowq = lane >> 4;
#pragma unroll
    for (int rt = 0; rt < 2; ++rt) {
#pragma unroll
        for (int reg = 0; reg < 4; ++reg) {
            int r = rowbase + rt * 16 + rowq * 4 + reg;
            if (r < NN) {
#pragma unroll
                for (int ct = 0; ct < 4; ++ct)
                    h[(size_t)r * OF + ct * 16 + c] = f2bf(acc[rt][ct][reg]);
                float sv = acc[rt][4][reg];
                if (c == 0)      s1[r] = sv;
                else if (c == 1) s2[r] = sv;
            }
        }
    }
}

// ---- part1: LDS hist -> window reservation -> packed scatter (own kernel) ----
__global__ __launch_bounds__(256) void k_part1(const int* __restrict__ idx,
                                               int* __restrict__ cur_b,
                                               int* __restrict__ pairs,
                                               int2* __restrict__ ov_list) {
    __shared__ int hist[NB];
    __shared__ int gbase[NB];
    int tid = threadIdx.x, blk = blockIdx.x;
    for (int i = tid; i < NB; i += 256) hist[i] = 0;
    __syncthreads();
    int e0 = blk * CH1, e1 = min(e0 + CH1, NE);
    for (int e = e0 + tid; e < e1; e += 256)
        atomicAdd(&hist[idx[e] >> 7], 1);
    __syncthreads();
    for (int i = tid; i < NB; i += 256) {
        int c = hist[i];
        gbase[i] = c ? atomicAdd(&cur_b[i], c) : 0;   // reserve window
        hist[i] = 0;                                   // reuse as local cursor
    }
    __syncthreads();
    for (int e = e0 + tid; e < e1; e += 256) {
        int s = idx[e], d = idx[NE + e];
        int b = s >> 7;
        int p = gbase[b] + atomicAdd(&hist[b], 1);
        if (p < CAPB) pairs[b * CAPB + p] = ((s & 127) << 17) | d;
        else {
            int j = atomicAdd(&cur_b[NB], 1);
            if (j < OVCAP) ov_list[j] = make_int2(s, d);
        }
    }
}

// ==== part2: per-bucket LDS sort -> start/deg; edge-parallel (dst,ex) out ====
__global__ __launch_bounds__(256) void k_part2(const int* __restrict__ pairs,
                                               const int* __restrict__ cur_b,
                                               const int2* __restrict__ ov_list,
                                               const float* __restrict__ s1,
                                               const float* __restrict__ s2,
                                               int* __restrict__ start,
                                               int* __restrict__ deg,
                                               int2* __restrict__ el_g) {
    __shared__ int stage[ED];
    __shared__ int cnt[NPB], pfx[NPB], cur[NPB];
    __shared__ float s1l[NPB];
    __shared__ int extra;
    int tid = threadIdx.x, b = blockIdx.x;
    int node0 = b * NPB;

    if (tid < NPB) {
        cnt[tid] = 0;
        int g = node0 + tid;
        s1l[tid] = (g < NN) ? s1[g] : 0.f;
    }
    if (tid == 0) extra = 0;
    __syncthreads();

    int t_b = cur_b[b];
    int nin = min(t_b, CAPB);
    for (int i = tid; i < nin; i += 256) {
        int v = pairs[b * CAPB + i];
        stage[i] = v;
        atomicAdd(&cnt[v >> 17], 1);
    }
    if (t_b > CAPB) {                    // rare-to-never overflow path
        int ovn = min(cur_b[NB], OVCAP);
        for (int i = tid; i < ovn; i += 256) {
            int2 e = ov_list[i];
            if ((e.x >> 7) == b) {
                int k = atomicAdd(&extra, 1);
                if (k < 128) {
                    stage[CAPB + k] = ((e.x & 127) << 17) | e.y;
                    atomicAdd(&cnt[e.x & 127], 1);
                }
            }
        }
    }
    __syncthreads();
    int ntot = nin + min(extra, 128);

    if (tid < NPB) pfx[tid] = cnt[tid];
    __syncthreads();
    for (int off = 1; off < NPB; off <<= 1) {
        int xv = (tid >= off && tid < NPB) ? pfx[tid - off] : 0;
        __syncthreads();
        if (tid < NPB) pfx[tid] += xv;
        __syncthreads();
    }
    if (tid < NPB) {
        int ex = pfx[tid] - cnt[tid];
        int g = node0 + tid;
        if (g < NN) { start[g] = b * CAPB + ex; deg[g] = cnt[tid]; }
        cur[tid] = ex;
    }
    __syncthreads();
    // scatter + attention weight, edge-parallel (256 thr)
    for (int i = tid; i < ntot; i += 256) {
        int v = stage[i];
        int ls = v >> 17, dst = v & 0x1FFFF;
        int p = atomicAdd(&cur[ls], 1);
        float lg = s1l[ls] + s2[dst];
        float elr = lg > 0.f ? lg : LRELU_ALPHA * lg;
        el_g[b * CAPB + p] = make_int2(dst, __float_as_int(expf(elr)));
    }
}

// ==== agg: 1 wave/node; coalesced (dst,ex) staging; half-wave j-loop ====
__global__ __launch_bounds__(256) void k_agg(const int2* __restrict__ el_g,
                                             const int* __restrict__ start,
                                             const int* __restrict__ deg,
                                             const unsigned short* __restrict__ h,
                                             float* __restrict__ out) {
    __shared__ int2 tile[4][64];
    int tid = threadIdx.x;
    int wid = tid >> 6, lane = tid & 63;
    int node = blockIdx.x * 4 + wid;
    if (node >= NN) return;

    int st = start[node];
    int dg = deg[node];
    int half = lane >> 5, f2 = lane & 31;
    float den = 0.f, ax = 0.f, ay = 0.f;

    for (int base = 0; base < dg; base += 64) {
        int cnt = min(64, dg - base);
        if (lane < cnt) {
            int2 pr = el_g[st + base + lane];      // coalesced 8B
            den += __int_as_float(pr.y);           // den out of the j-loop
            tile[wid][lane] = pr;
        }
        asm volatile("s_waitcnt lgkmcnt(0)" ::: "memory");
#pragma unroll 4
        for (int j = half; j < cnt; j += 2) {      // halves take alternating edges
            int2 e = tile[wid][j];                 // broadcast ds_read_b64 (2 addrs/wave)
            float ex = __int_as_float(e.y);
            unsigned int hv = *(const unsigned int*)(h + (size_t)e.x * OF + f2 * 2);
            ax += ex * bf2f((unsigned short)(hv & 0xFFFFu));
            ay += ex * bf2f((unsigned short)(hv >> 16));
        }
        asm volatile("" ::: "memory");
    }

    // reduce: den across all 64 lanes; ax/ay across the two halves
#pragma unroll
    for (int off = 1; off < 64; off <<= 1) den += __shfl_xor(den, off, 64);
    ax += __shfl_xor(ax, 32, 64);
    ay += __shfl_xor(ay, 32, 64);

    float inv = den > 0.f ? 1.f / den : 0.f;
    float vx = ax * inv, vy = ay * inv;
    vx = vx > 0.f ? vx : expf(vx) - 1.f;
    vy = vy > 0.f ? vy : expf(vy) - 1.f;
    if (half == 0)
        *(float2*)(out + (size_t)node * OF + f2 * 2) = make_float2(vx, vy);
}

extern "C" void kernel_launch(void* const* d_in, const int* in_sizes, int n_in,
                              void* d_out, int out_size, void* d_ws, size_t ws_size,
                              hipStream_t stream) {
    const float* x   = (const float*)d_in[0];
    const int*   idx = (const int*)d_in[1];
    const float* W   = (const float*)d_in[2];
    const float* a   = (const float*)d_in[3];
    float* out = (float*)d_out;

    char* ws = (char*)d_ws;
    unsigned short* h = (unsigned short*)ws;  ws += sizeof(unsigned short) * (size_t)NN * OF;
    int*  pairs       = (int*)ws;             ws += sizeof(int) * (size_t)NB * CAPB;
    int2* el_g        = (int2*)ws;            ws += sizeof(int2) * (size_t)NB * CAPB;
    float* s1         = (float*)ws;           ws += sizeof(float) * NN;
    float* s2         = (float*)ws;           ws += sizeof(float) * NN;
    int*   start      = (int*)ws;             ws += sizeof(int) * NN;
    int*   deg        = (int*)ws;             ws += sizeof(int) * NN;
    int*   cur_b      = (int*)ws;             ws += sizeof(int) * (NB + 16);  // [NB] = ov count
    int2*  ov_list    = (int2*)ws;            ws += sizeof(int2) * OVCAP;
    float* wa         = (float*)ws;           ws += sizeof(float) * 512;

    hipMemsetAsync(cur_b, 0, sizeof(int) * (NB + 16), stream);
    k_prep<<<1, 256, 0, stream>>>(W, a, wa);
    k_gemm<<<GEMMB, 256, 0, stream>>>(x, W, wa, h, s1, s2);
    k_part1<<<P1B, 256, 0, stream>>>(idx, cur_b, pairs, ov_list);
    k_part2<<<NB, 256, 0, stream>>>(pairs, cur_b, ov_list, s1, s2, start, deg, el_g);
    k_agg<<<(NN + 3) / 4, 256, 0, stream>>>(el_g, start, deg, h, out);
}

// Round 13
// 288.767 us; speedup vs baseline: 1.0260x; 1.0260x over previous
//
#include <hip/hip_runtime.h>
#include <hip/hip_bf16.h>
#include <math.h>

#define NN 100000
#define NE 1600000
#define INF_ 256
#define OF 64

#define NPB 128                      // nodes per bucket (bucket = src >> 7)
#define NB  782                      // ceil(NN/NPB)
#define CAPB 2560                    // fixed bucket capacity (mean 2048, +11 sigma)
#define ED (CAPB + 128)
#define GEMMB 782                    // ceil(NN/128) gemm blocks
#define P1B 512                      // part1 blocks
#define CH1 ((NE + P1B - 1) / P1B)   // 3125 edges/block
#define OVCAP 8192

constexpr float LRELU_ALPHA = 0.2f;

typedef __attribute__((ext_vector_type(8))) short short8;
typedef __attribute__((ext_vector_type(4))) float f32x4;

static __device__ __forceinline__ unsigned short f2bf(float f) {
    union { float f; unsigned int u; } v; v.f = f;
    unsigned int r = v.u + 0x7fff + ((v.u >> 16) & 1);   // RNE
    return (unsigned short)(r >> 16);
}
static __device__ __forceinline__ float bf2f(unsigned short b) {
    union { unsigned int u; float f; } v; v.u = ((unsigned int)b) << 16;
    return v.f;
}
static __device__ __forceinline__ unsigned int pkbf(float a, float b) {
    union { __hip_bfloat162 h; unsigned int u; } c;
    c.h = __float22bfloat162_rn(make_float2(a, b));
    return c.u;
}

union S8 { short8 s; unsigned int u[4]; };

// ---------------- wa1 = W @ a1, wa2 = W @ a2 ----------------
__global__ __launch_bounds__(256) void k_prep(const float* __restrict__ W,
                                              const float* __restrict__ a,
                                              float* __restrict__ wa) {
    int r = threadIdx.x;
    float t1 = 0.f, t2 = 0.f;
#pragma unroll 8
    for (int c = 0; c < OF; ++c) {
        float w = W[r * OF + c];
        t1 += w * a[c];
        t2 += w * a[OF + c];
    }
    wa[r] = t1;
    wa[256 + r] = t2;
}

// ====== fused1: [0,GEMMB) = gemm (32KB LDS, frag5 in regs, full unroll) ======
// ======         [GEMMB, GEMMB+P1B) = part1 (hist->reserve->scatter)     ======
__global__ __launch_bounds__(256, 3) void k_fused1(const float* __restrict__ x,
                                                   const float* __restrict__ W,
                                                   const float* __restrict__ wa,
                                                   const int* __restrict__ idx,
                                                   int* __restrict__ cur_b,
                                                   int* __restrict__ pairs,
                                                   int2* __restrict__ ov_list,
                                                   unsigned short* __restrict__ h,
                                                   float* __restrict__ s1,
                                                   float* __restrict__ s2) {
    __shared__ __align__(16) char smem[32768];   // gemm: Wf 4 tiles | part1: 2*NB ints (6.3KB)
    int tid = threadIdx.x;

    if (blockIdx.x < GEMMB) {
        // ---------------- gemm branch ----------------
        short* Wf = (short*)smem;      // [ks(8)][ct(4)][lane(64)][8 bf16] = 32768 B
        for (int i = tid; i < 2048; i += 256) {
            int ks = i >> 8;
            int ct = (i >> 6) & 3;
            int l  = i & 63;
            int kb = ks * 32 + ((l >> 4) << 3);
            int col = ct * 16 + (l & 15);
            S8 v;
#pragma unroll
            for (int j = 0; j < 4; ++j)
                v.u[j] = pkbf(W[(size_t)(kb + 2 * j) * OF + col],
                              W[(size_t)(kb + 2 * j + 1) * OF + col]);
            ((short8*)Wf)[i] = v.s;
        }

        int wid = tid >> 6, lane = tid & 63;
        int rowbase = blockIdx.x * 128 + wid * 32;
        int c = lane & 15;
        int koff = (lane >> 4) << 3;

        // 5th B-tile (wa columns 0,1) in registers: 8 x short8 = 32 VGPR
        short8 frag5[8];
        {
#pragma unroll
            for (int ks = 0; ks < 8; ++ks) {
                S8 v;
                if (c < 2) {
                    const float* src = wa + c * 256 + ks * 32 + koff;
                    float4 u0 = *(const float4*)src;
                    float4 u1 = *(const float4*)(src + 4);
                    v.u[0] = pkbf(u0.x, u0.y); v.u[1] = pkbf(u0.z, u0.w);
                    v.u[2] = pkbf(u1.x, u1.y); v.u[3] = pkbf(u1.z, u1.w);
                } else {
                    v.u[0] = 0u; v.u[1] = 0u; v.u[2] = 0u; v.u[3] = 0u;
                }
                frag5[ks] = v.s;
            }
        }
        __syncthreads();

        // clamped row addressing: branchless loads, epilogue guards r<NN
        int r0 = rowbase + c;
        int rc0 = min(r0, NN - 1);
        int rc1 = min(r0 + 16, NN - 1);
        const float* p0 = x + (size_t)rc0 * INF_ + koff;
        const float* p1 = x + (size_t)rc1 * INF_ + koff;

        f32x4 acc[2][5];
#pragma unroll
        for (int rt = 0; rt < 2; ++rt)
#pragma unroll
            for (int ct = 0; ct < 5; ++ct) acc[rt][ct] = (f32x4){0.f, 0.f, 0.f, 0.f};

#pragma unroll
        for (int ks = 0; ks < 8; ++ks) {
            float4 xa0 = *(const float4*)(p0 + ks * 32);
            float4 xb0 = *(const float4*)(p0 + ks * 32 + 4);
            float4 xa1 = *(const float4*)(p1 + ks * 32);
            float4 xb1 = *(const float4*)(p1 + ks * 32 + 4);
            S8 af[2];
            af[0].u[0] = pkbf(xa0.x, xa0.y); af[0].u[1] = pkbf(xa0.z, xa0.w);
            af[0].u[2] = pkbf(xb0.x, xb0.y); af[0].u[3] = pkbf(xb0.z, xb0.w);
            af[1].u[0] = pkbf(xa1.x, xa1.y); af[1].u[1] = pkbf(xa1.z, xa1.w);
            af[1].u[2] = pkbf(xb1.x, xb1.y); af[1].u[3] = pkbf(xb1.z, xb1.w);
#pragma unroll
            for (int rt = 0; rt < 2; ++rt) {
#pragma unroll
                for (int ct = 0; ct < 4; ++ct)
                    acc[rt][ct] = __builtin_amdgcn_mfma_f32_16x16x32_bf16(
                        af[rt].s, ((short8*)Wf)[(ks * 4 + ct) * 64 + lane], acc[rt][ct], 0, 0, 0);
                acc[rt][4] = __builtin_amdgcn_mfma_f32_16x16x32_bf16(
                    af[rt].s, frag5[ks], acc[rt][4], 0, 0, 0);
            }
        }

        int rowq = lane >> 4;
#pragma unroll
        for (int rt = 0; rt < 2; ++rt) {
#pragma unroll
            for (int reg = 0; reg < 4; ++reg) {
                int r = rowbase + rt * 16 + rowq * 4 + reg;
                if (r < NN) {
#pragma unroll
                    for (int ct = 0; ct < 4; ++ct)
                        h[(size_t)r * OF + ct * 16 + c] = f2bf(acc[rt][ct][reg]);
                    float sv = acc[rt][4][reg];
                    if (c == 0)      s1[r] = sv;
                    else if (c == 1) s2[r] = sv;
                }
            }
        }
    } else {
        // ---------------- part1 branch ----------------
        int blk = blockIdx.x - GEMMB;
        int* hist  = (int*)smem;        // [NB]
        int* gbase = (int*)smem + NB;   // [NB]
        for (int i = tid; i < NB; i += 256) hist[i] = 0;
        __syncthreads();
        int e0 = blk * CH1, e1 = min(e0 + CH1, NE);
        for (int e = e0 + tid; e < e1; e += 256)
            atomicAdd(&hist[idx[e] >> 7], 1);
        __syncthreads();
        for (int i = tid; i < NB; i += 256) {
            int cc = hist[i];
            gbase[i] = cc ? atomicAdd(&cur_b[i], cc) : 0;   // reserve window
            hist[i] = 0;                                     // reuse as local cursor
        }
        __syncthreads();
        for (int e = e0 + tid; e < e1; e += 256) {
            int s = idx[e], d = idx[NE + e];
            int b = s >> 7;
            int p = gbase[b] + atomicAdd(&hist[b], 1);
            if (p < CAPB) pairs[b * CAPB + p] = ((s & 127) << 17) | d;
            else {
                int j = atomicAdd(&cur_b[NB], 1);
                if (j < OVCAP) ov_list[j] = make_int2(s, d);
            }
        }
    }
}

// ==== part2: per-bucket LDS sort -> start/deg; edge-parallel (dst,ex) out ====
__global__ __launch_bounds__(256) void k_part2(const int* __restrict__ pairs,
                                               const int* __restrict__ cur_b,
                                               const int2* __restrict__ ov_list,
                                               const float* __restrict__ s1,
                                               const float* __restrict__ s2,
                                               int* __restrict__ start,
                                               int* __restrict__ deg,
                                               int2* __restrict__ el_g) {
    __shared__ int stage[ED];
    __shared__ int cnt[NPB], pfx[NPB], cur[NPB];
    __shared__ float s1l[NPB];
    __shared__ int extra;
    int tid = threadIdx.x, b = blockIdx.x;
    int node0 = b * NPB;

    if (tid < NPB) {
        cnt[tid] = 0;
        int g = node0 + tid;
        s1l[tid] = (g < NN) ? s1[g] : 0.f;
    }
    if (tid == 0) extra = 0;
    __syncthreads();

    int t_b = cur_b[b];
    int nin = min(t_b, CAPB);
    for (int i = tid; i < nin; i += 256) {
        int v = pairs[b * CAPB + i];
        stage[i] = v;
        atomicAdd(&cnt[v >> 17], 1);
    }
    if (t_b > CAPB) {                    // rare-to-never overflow path
        int ovn = min(cur_b[NB], OVCAP);
        for (int i = tid; i < ovn; i += 256) {
            int2 e = ov_list[i];
            if ((e.x >> 7) == b) {
                int k = atomicAdd(&extra, 1);
                if (k < 128) {
                    stage[CAPB + k] = ((e.x & 127) << 17) | e.y;
                    atomicAdd(&cnt[e.x & 127], 1);
                }
            }
        }
    }
    __syncthreads();
    int ntot = nin + min(extra, 128);

    if (tid < NPB) pfx[tid] = cnt[tid];
    __syncthreads();
    for (int off = 1; off < NPB; off <<= 1) {
        int xv = (tid >= off && tid < NPB) ? pfx[tid - off] : 0;
        __syncthreads();
        if (tid < NPB) pfx[tid] += xv;
        __syncthreads();
    }
    if (tid < NPB) {
        int ex = pfx[tid] - cnt[tid];
        int g = node0 + tid;
        if (g < NN) { start[g] = b * CAPB + ex; deg[g] = cnt[tid]; }
        cur[tid] = ex;
    }
    __syncthreads();
    // scatter + attention weight, edge-parallel (256 thr)
    for (int i = tid; i < ntot; i += 256) {
        int v = stage[i];
        int ls = v >> 17, dst = v & 0x1FFFF;
        int p = atomicAdd(&cur[ls], 1);
        float lg = s1l[ls] + s2[dst];
        float elr = lg > 0.f ? lg : LRELU_ALPHA * lg;
        el_g[b * CAPB + p] = make_int2(dst, __float_as_int(expf(elr)));
    }
}

// ==== agg: 1 wave/node; coalesced (dst,ex) staging; half-wave j-loop ====
__global__ __launch_bounds__(256) void k_agg(const int2* __restrict__ el_g,
                                             const int* __restrict__ start,
                                             const int* __restrict__ deg,
                                             const unsigned short* __restrict__ h,
                                             float* __restrict__ out) {
    __shared__ int2 tile[4][64];
    int tid = threadIdx.x;
    int wid = tid >> 6, lane = tid & 63;
    int node = blockIdx.x * 4 + wid;
    if (node >= NN) return;

    int st = start[node];
    int dg = deg[node];
    int half = lane >> 5, f2 = lane & 31;
    float den = 0.f, ax = 0.f, ay = 0.f;

    for (int base = 0; base < dg; base += 64) {
        int cnt = min(64, dg - base);
        if (lane < cnt) {
            int2 pr = el_g[st + base + lane];      // coalesced 8B
            den += __int_as_float(pr.y);           // den out of the j-loop
            tile[wid][lane] = pr;
        }
        asm volatile("s_waitcnt lgkmcnt(0)" ::: "memory");
#pragma unroll 4
        for (int j = half; j < cnt; j += 2) {      // halves take alternating edges
            int2 e = tile[wid][j];                 // broadcast ds_read_b64 (2 addrs/wave)
            float ex = __int_as_float(e.y);
            unsigned int hv = *(const unsigned int*)(h + (size_t)e.x * OF + f2 * 2);
            ax += ex * bf2f((unsigned short)(hv & 0xFFFFu));
            ay += ex * bf2f((unsigned short)(hv >> 16));
        }
        asm volatile("" ::: "memory");
    }

    // reduce: den across all 64 lanes; ax/ay across the two halves
#pragma unroll
    for (int off = 1; off < 64; off <<= 1) den += __shfl_xor(den, off, 64);
    ax += __shfl_xor(ax, 32, 64);
    ay += __shfl_xor(ay, 32, 64);

    float inv = den > 0.f ? 1.f / den : 0.f;
    float vx = ax * inv, vy = ay * inv;
    vx = vx > 0.f ? vx : expf(vx) - 1.f;
    vy = vy > 0.f ? vy : expf(vy) - 1.f;
    if (half == 0)
        *(float2*)(out + (size_t)node * OF + f2 * 2) = make_float2(vx, vy);
}

extern "C" void kernel_launch(void* const* d_in, const int* in_sizes, int n_in,
                              void* d_out, int out_size, void* d_ws, size_t ws_size,
                              hipStream_t stream) {
    const float* x   = (const float*)d_in[0];
    const int*   idx = (const int*)d_in[1];
    const float* W   = (const float*)d_in[2];
    const float* a   = (const float*)d_in[3];
    float* out = (float*)d_out;

    char* ws = (char*)d_ws;
    unsigned short* h = (unsigned short*)ws;  ws += sizeof(unsigned short) * (size_t)NN * OF;
    int*  pairs       = (int*)ws;             ws += sizeof(int) * (size_t)NB * CAPB;
    int2* el_g        = (int2*)ws;            ws += sizeof(int2) * (size_t)NB * CAPB;
    float* s1         = (float*)ws;           ws += sizeof(float) * NN;
    float* s2         = (float*)ws;           ws += sizeof(float) * NN;
    int*   start      = (int*)ws;             ws += sizeof(int) * NN;
    int*   deg        = (int*)ws;             ws += sizeof(int) * NN;
    int*   cur_b      = (int*)ws;             ws += sizeof(int) * (NB + 16);  // [NB] = ov count
    int2*  ov_list    = (int2*)ws;            ws += sizeof(int2) * OVCAP;
    float* wa         = (float*)ws;           ws += sizeof(float) * 512;

    hipMemsetAsync(cur_b, 0, sizeof(int) * (NB + 16), stream);
    k_prep<<<1, 256, 0, stream>>>(W, a, wa);
    k_fused1<<<GEMMB + P1B, 256, 0, stream>>>(x, W, wa, idx, cur_b, pairs, ov_list, h, s1, s2);
    k_part2<<<NB, 256, 0, stream>>>(pairs, cur_b, ov_list, s1, s2, start, deg, el_g);
    k_agg<<<(NN + 3) / 4, 256, 0, stream>>>(el_g, start, deg, h, out);
}

// Round 14
// 278.843 us; speedup vs baseline: 1.0625x; 1.0356x over previous
//
#include <hip/hip_runtime.h>
#include <hip/hip_bf16.h>
#include <math.h>

#define NN 100000
#define NE 1600000
#define INF_ 256
#define OF 64

#define NPB 128                      // nodes per bucket (bucket = src >> 7)
#define NB  782                      // ceil(NN/NPB)
#define CAPB 2560                    // fixed bucket capacity (mean 2048, +11 sigma)
#define ED (CAPB + 128)
#define GEMMB 782                    // ceil(NN/128) gemm blocks
#define P1B 512                      // part1 blocks
#define CH1 ((NE + P1B - 1) / P1B)   // 3125 edges/block
#define OVCAP 8192

constexpr float LRELU_ALPHA = 0.2f;

typedef __attribute__((ext_vector_type(8))) short short8;
typedef __attribute__((ext_vector_type(4))) float f32x4;

static __device__ __forceinline__ unsigned short f2bf(float f) {
    union { float f; unsigned int u; } v; v.f = f;
    unsigned int r = v.u + 0x7fff + ((v.u >> 16) & 1);   // RNE
    return (unsigned short)(r >> 16);
}
static __device__ __forceinline__ float bf2f(unsigned short b) {
    union { unsigned int u; float f; } v; v.u = ((unsigned int)b) << 16;
    return v.f;
}
static __device__ __forceinline__ unsigned int pkbf(float a, float b) {
    union { __hip_bfloat162 h; unsigned int u; } c;
    c.h = __float22bfloat162_rn(make_float2(a, b));
    return c.u;
}

union S8 { short8 s; unsigned int u[4]; };

// ====== fused1 (512 thr): [0,GEMMB) = gemm, 8 waves x 16 rows, TLP-heavy ======
// ======                   [GEMMB,+P1B) = part1 (hist->reserve->scatter)  ======
__global__ __launch_bounds__(512, 6) void k_fused1(const float* __restrict__ x,
                                                   const float* __restrict__ W,
                                                   const float* __restrict__ a,
                                                   const int* __restrict__ idx,
                                                   int* __restrict__ cur_b,
                                                   int* __restrict__ pairs,
                                                   int2* __restrict__ ov_list,
                                                   unsigned short* __restrict__ h,
                                                   float* __restrict__ s1,
                                                   float* __restrict__ s2) {
    __shared__ __align__(16) char smem[34816];   // gemm: Wf 32KB + wal 2KB | part1: 2*NB ints
    int tid = threadIdx.x;

    if (blockIdx.x < GEMMB) {
        // ---------------- gemm branch ----------------
        short* Wf  = (short*)smem;                 // [ks(8)][ct(4)][lane(64)][8 bf16] = 32 KB
        float* wal = (float*)(smem + 32768);       // wa1[256], wa2[256]

        if (tid < 256) {   // folded k_prep (W is L2-hot)
            float t1 = 0.f, t2 = 0.f;
            const float* wr = W + tid * OF;
#pragma unroll 8
            for (int cc = 0; cc < OF; ++cc) {
                float w = wr[cc];
                t1 += w * a[cc];
                t2 += w * a[OF + cc];
            }
            wal[tid] = t1;
            wal[256 + tid] = t2;
        }
        for (int i = tid; i < 2048; i += 512) {
            int ks = i >> 8;
            int ct = (i >> 6) & 3;
            int l  = i & 63;
            int kb = ks * 32 + ((l >> 4) << 3);
            int col = ct * 16 + (l & 15);
            S8 v;
#pragma unroll
            for (int j = 0; j < 4; ++j)
                v.u[j] = pkbf(W[(size_t)(kb + 2 * j) * OF + col],
                              W[(size_t)(kb + 2 * j + 1) * OF + col]);
            ((short8*)Wf)[i] = v.s;
        }
        __syncthreads();

        int wid = tid >> 6, lane = tid & 63;
        int rowbase = blockIdx.x * 128 + wid * 16;   // 16 rows per wave
        int c = lane & 15;
        int koff = (lane >> 4) << 3;

        // 5th B-tile (wa cols 0,1) in regs: 8 x short8 = 32 VGPR, read from LDS wal
        short8 frag5[8];
#pragma unroll
        for (int ks = 0; ks < 8; ++ks) {
            S8 v;
            if (c < 2) {
                const float* src = wal + c * 256 + ks * 32 + koff;
                v.u[0] = pkbf(src[0], src[1]); v.u[1] = pkbf(src[2], src[3]);
                v.u[2] = pkbf(src[4], src[5]); v.u[3] = pkbf(src[6], src[7]);
            } else {
                v.u[0] = 0u; v.u[1] = 0u; v.u[2] = 0u; v.u[3] = 0u;
            }
            frag5[ks] = v.s;
        }

        int r0 = rowbase + c;
        int rc0 = min(r0, NN - 1);                   // clamped; epilogue guards
        const float* p0 = x + (size_t)rc0 * INF_ + koff;

        f32x4 acc[5];
#pragma unroll
        for (int ct = 0; ct < 5; ++ct) acc[ct] = (f32x4){0.f, 0.f, 0.f, 0.f};

#pragma unroll
        for (int ks = 0; ks < 8; ++ks) {
            float4 xa = *(const float4*)(p0 + ks * 32);
            float4 xb = *(const float4*)(p0 + ks * 32 + 4);
            S8 af;
            af.u[0] = pkbf(xa.x, xa.y); af.u[1] = pkbf(xa.z, xa.w);
            af.u[2] = pkbf(xb.x, xb.y); af.u[3] = pkbf(xb.z, xb.w);
#pragma unroll
            for (int ct = 0; ct < 4; ++ct)
                acc[ct] = __builtin_amdgcn_mfma_f32_16x16x32_bf16(
                    af.s, ((short8*)Wf)[(ks * 4 + ct) * 64 + lane], acc[ct], 0, 0, 0);
            acc[4] = __builtin_amdgcn_mfma_f32_16x16x32_bf16(
                af.s, frag5[ks], acc[4], 0, 0, 0);
        }

        int rowq = lane >> 4;
#pragma unroll
        for (int reg = 0; reg < 4; ++reg) {
            int r = rowbase + rowq * 4 + reg;
            if (r < NN) {
#pragma unroll
                for (int ct = 0; ct < 4; ++ct)
                    h[(size_t)r * OF + ct * 16 + c] = f2bf(acc[ct][reg]);
                float sv = acc[4][reg];
                if (c == 0)      s1[r] = sv;
                else if (c == 1) s2[r] = sv;
            }
        }
    } else {
        // ---------------- part1 branch (512 thr) ----------------
        int blk = blockIdx.x - GEMMB;
        int* hist  = (int*)smem;        // [NB]
        int* gbase = (int*)smem + NB;   // [NB]
        for (int i = tid; i < NB; i += 512) hist[i] = 0;
        __syncthreads();
        int e0 = blk * CH1, e1 = min(e0 + CH1, NE);
        for (int e = e0 + tid; e < e1; e += 512)
            atomicAdd(&hist[idx[e] >> 7], 1);
        __syncthreads();
        for (int i = tid; i < NB; i += 512) {
            int cc = hist[i];
            gbase[i] = cc ? atomicAdd(&cur_b[i], cc) : 0;   // reserve window
            hist[i] = 0;                                     // reuse as local cursor
        }
        __syncthreads();
        for (int e = e0 + tid; e < e1; e += 512) {
            int s = idx[e], d = idx[NE + e];
            int b = s >> 7;
            int p = gbase[b] + atomicAdd(&hist[b], 1);
            if (p < CAPB) pairs[b * CAPB + p] = ((s & 127) << 17) | d;
            else {
                int j = atomicAdd(&cur_b[NB], 1);
                if (j < OVCAP) ov_list[j] = make_int2(s, d);
            }
        }
    }
}

// ==== part2: per-bucket LDS sort -> start/deg; edge-parallel (dst,ex) out ====
__global__ __launch_bounds__(256) void k_part2(const int* __restrict__ pairs,
                                               const int* __restrict__ cur_b,
                                               const int2* __restrict__ ov_list,
                                               const float* __restrict__ s1,
                                               const float* __restrict__ s2,
                                               int* __restrict__ start,
                                               int* __restrict__ deg,
                                               int2* __restrict__ el_g) {
    __shared__ int stage[ED];
    __shared__ int cnt[NPB], pfx[NPB], cur[NPB];
    __shared__ float s1l[NPB];
    __shared__ int extra;
    int tid = threadIdx.x, b = blockIdx.x;
    int node0 = b * NPB;

    if (tid < NPB) {
        cnt[tid] = 0;
        int g = node0 + tid;
        s1l[tid] = (g < NN) ? s1[g] : 0.f;
    }
    if (tid == 0) extra = 0;
    __syncthreads();

    int t_b = cur_b[b];
    int nin = min(t_b, CAPB);
    for (int i = tid; i < nin; i += 256) {
        int v = pairs[b * CAPB + i];
        stage[i] = v;
        atomicAdd(&cnt[v >> 17], 1);
    }
    if (t_b > CAPB) {                    // rare-to-never overflow path
        int ovn = min(cur_b[NB], OVCAP);
        for (int i = tid; i < ovn; i += 256) {
            int2 e = ov_list[i];
            if ((e.x >> 7) == b) {
                int k = atomicAdd(&extra, 1);
                if (k < 128) {
                    stage[CAPB + k] = ((e.x & 127) << 17) | e.y;
                    atomicAdd(&cnt[e.x & 127], 1);
                }
            }
        }
    }
    __syncthreads();
    int ntot = nin + min(extra, 128);

    if (tid < NPB) pfx[tid] = cnt[tid];
    __syncthreads();
    for (int off = 1; off < NPB; off <<= 1) {
        int xv = (tid >= off && tid < NPB) ? pfx[tid - off] : 0;
        __syncthreads();
        if (tid < NPB) pfx[tid] += xv;
        __syncthreads();
    }
    if (tid < NPB) {
        int ex = pfx[tid] - cnt[tid];
        int g = node0 + tid;
        if (g < NN) { start[g] = b * CAPB + ex; deg[g] = cnt[tid]; }
        cur[tid] = ex;
    }
    __syncthreads();
    // scatter + attention weight, edge-parallel (256 thr)
    for (int i = tid; i < ntot; i += 256) {
        int v = stage[i];
        int ls = v >> 17, dst = v & 0x1FFFF;
        int p = atomicAdd(&cur[ls], 1);
        float lg = s1l[ls] + s2[dst];
        float elr = lg > 0.f ? lg : LRELU_ALPHA * lg;
        el_g[b * CAPB + p] = make_int2(dst, __float_as_int(expf(elr)));
    }
}

// ==== agg: 1 wave/node; coalesced (dst,ex) staging; half-wave j-loop ====
__global__ __launch_bounds__(256) void k_agg(const int2* __restrict__ el_g,
                                             const int* __restrict__ start,
                                             const int* __restrict__ deg,
                                             const unsigned short* __restrict__ h,
                                             float* __restrict__ out) {
    __shared__ int2 tile[4][64];
    int tid = threadIdx.x;
    int wid = tid >> 6, lane = tid & 63;
    int node = blockIdx.x * 4 + wid;
    if (node >= NN) return;

    int st = start[node];
    int dg = deg[node];
    int half = lane >> 5, f2 = lane & 31;
    float den = 0.f, ax = 0.f, ay = 0.f;

    for (int base = 0; base < dg; base += 64) {
        int cnt = min(64, dg - base);
        if (lane < cnt) {
            int2 pr = el_g[st + base + lane];      // coalesced 8B
            den += __int_as_float(pr.y);           // den out of the j-loop
            tile[wid][lane] = pr;
        }
        asm volatile("s_waitcnt lgkmcnt(0)" ::: "memory");
#pragma unroll 4
        for (int j = half; j < cnt; j += 2) {      // halves take alternating edges
            int2 e = tile[wid][j];                 // broadcast ds_read_b64 (2 addrs/wave)
            float ex = __int_as_float(e.y);
            unsigned int hv = *(const unsigned int*)(h + (size_t)e.x * OF + f2 * 2);
            ax += ex * bf2f((unsigned short)(hv & 0xFFFFu));
            ay += ex * bf2f((unsigned short)(hv >> 16));
        }
        asm volatile("" ::: "memory");
    }

    // reduce: den across all 64 lanes; ax/ay across the two halves
#pragma unroll
    for (int off = 1; off < 64; off <<= 1) den += __shfl_xor(den, off, 64);
    ax += __shfl_xor(ax, 32, 64);
    ay += __shfl_xor(ay, 32, 64);

    float inv = den > 0.f ? 1.f / den : 0.f;
    float vx = ax * inv, vy = ay * inv;
    vx = vx > 0.f ? vx : expf(vx) - 1.f;
    vy = vy > 0.f ? vy : expf(vy) - 1.f;
    if (half == 0)
        *(float2*)(out + (size_t)node * OF + f2 * 2) = make_float2(vx, vy);
}

extern "C" void kernel_launch(void* const* d_in, const int* in_sizes, int n_in,
                              void* d_out, int out_size, void* d_ws, size_t ws_size,
                              hipStream_t stream) {
    const float* x   = (const float*)d_in[0];
    const int*   idx = (const int*)d_in[1];
    const float* W   = (const float*)d_in[2];
    const float* a   = (const float*)d_in[3];
    float* out = (float*)d_out;

    char* ws = (char*)d_ws;
    unsigned short* h = (unsigned short*)ws;  ws += sizeof(unsigned short) * (size_t)NN * OF;
    int*  pairs       = (int*)ws;             ws += sizeof(int) * (size_t)NB * CAPB;
    int2* el_g        = (int2*)ws;            ws += sizeof(int2) * (size_t)NB * CAPB;
    float* s1         = (float*)ws;           ws += sizeof(float) * NN;
    float* s2         = (float*)ws;           ws += sizeof(float) * NN;
    int*   start      = (int*)ws;             ws += sizeof(int) * NN;
    int*   deg        = (int*)ws;             ws += sizeof(int) * NN;
    int*   cur_b      = (int*)ws;             ws += sizeof(int) * (NB + 16);  // [NB] = ov count
    int2*  ov_list    = (int2*)ws;            ws += sizeof(int2) * OVCAP;

    hipMemsetAsync(cur_b, 0, sizeof(int) * (NB + 16), stream);
    k_fused1<<<GEMMB + P1B, 512, 0, stream>>>(x, W, a, idx, cur_b, pairs, ov_list, h, s1, s2);
    k_part2<<<NB, 256, 0, stream>>>(pairs, cur_b, ov_list, s1, s2, start, deg, el_g);
    k_agg<<<(NN + 3) / 4, 256, 0, stream>>>(el_g, start, deg, h, out);
}